// Round 1
// baseline (421.379 us; speedup 1.0000x reference)
//
#include <hip/hip_runtime.h>
#include <stdint.h>

// ---------------------------------------------------------------------------
// CrossAttention_43061342110469 — algebraic reduction:
// einsum('bvhd,bhqk->bvhd', v, softmax(scores)) == v * L  (softmax rows sum
// to 1; summed over q gives L=2048). So out = 2048*(x @ Wv @ Wo) + const.
// encoder_x / Wq / bq / Wk / bk do not affect the output.
// ---------------------------------------------------------------------------

typedef __attribute__((ext_vector_type(8))) short bf16x8;
typedef __attribute__((ext_vector_type(4))) float f32x4;

typedef __attribute__((address_space(1))) void as1_void;
typedef __attribute__((address_space(3))) void as3_void;
#define GLD16(g, s)                                                          \
  __builtin_amdgcn_global_load_lds((as1_void*)(g), (as3_void*)(s), 16, 0, 0)

__device__ __forceinline__ short f2bf(float f) {
  union { float f; uint32_t u; } v; v.f = f;
  uint32_t r = v.u + 0x7FFFu + ((v.u >> 16) & 1u);  // round-to-nearest-even
  return (short)(r >> 16);
}

// ---- fp32 -> bf16 cast, 8 elems/thread, fully vectorized -------------------
__global__ __launch_bounds__(256) void cast_f32_bf16(
    const float* __restrict__ in, short* __restrict__ out, int n8) {
  int i = blockIdx.x * blockDim.x + threadIdx.x;
  if (i >= n8) return;
  const float4* p = (const float4*)in;
  float4 a = p[2 * (size_t)i], b = p[2 * (size_t)i + 1];
  bf16x8 o;
  o[0] = f2bf(a.x); o[1] = f2bf(a.y); o[2] = f2bf(a.z); o[3] = f2bf(a.w);
  o[4] = f2bf(b.x); o[5] = f2bf(b.y); o[6] = f2bf(b.z); o[7] = f2bf(b.w);
  *(bf16x8*)(out + 8 * (size_t)i) = o;
}

// ---- 1024x1024 fp32 -> bf16 transpose-cast (64x64 tiles via LDS) -----------
__global__ __launch_bounds__(256) void transpose_cast(
    const float* __restrict__ in, short* __restrict__ out, int n) {
  __shared__ float tile[64][65];
  const int br = blockIdx.y * 64;  // input row base
  const int bc = blockIdx.x * 64;  // input col base
  const int tid = threadIdx.x;
#pragma unroll
  for (int t = 0; t < 16; ++t) {
    int idx = t * 256 + tid;
    int r = idx >> 6, c = idx & 63;
    tile[r][c] = in[(size_t)(br + r) * n + bc + c];
  }
  __syncthreads();
#pragma unroll
  for (int t = 0; t < 16; ++t) {
    int idx = t * 256 + tid;
    int r = idx >> 6, c = idx & 63;  // output row = bc+r (orig col)
    out[(size_t)(bc + r) * n + br + c] = f2bf(tile[c][r]);
  }
}

// ---- bias_c[n] = 2048 * sum_k bv[k]*Wo[k,n] + bo[n]  (fp32, tiny) ----------
__global__ __launch_bounds__(256) void bias_fuse(
    const float* __restrict__ bv, const float* __restrict__ Wo,
    const float* __restrict__ bo, float* __restrict__ biasc, int D, int N) {
  int n = blockIdx.x * blockDim.x + threadIdx.x;
  if (n >= N) return;
  float s = 0.f;
  for (int k = 0; k < D; ++k) s += bv[k] * Wo[(size_t)k * N + n];
  biasc[n] = 2048.0f * s + bo[n];
}

// ---- C = A @ Bt^T  (Bt given row-major [N,K]); m97-style MFMA GEMM ---------
// BM=BN=128, BK=32, 256 threads (4 waves), each wave a 64x64 sub-tile as a
// 4x4 grid of 16x16x32 bf16 MFMAs. Staging via global_load_lds width=16.
// BF16_OUT: store bf16 with *scale (no bias). Else: fp32 with + bias[col].
template <bool BF16_OUT>
__global__ __launch_bounds__(256) void gemm_bt(
    const short* __restrict__ A, const short* __restrict__ Bt,
    const float* __restrict__ bias, void* __restrict__ Cout,
    int M, int N, int K, float scale) {
  constexpr int BM = 128, BN = 128, BK = 32;
  __shared__ __align__(16) short As[BM * BK];
  __shared__ __align__(16) short Bs[BN * BK];

  const int tid = threadIdx.x;
  const int lane = tid & 63;
  const int wave = tid >> 6;
  const int bm = blockIdx.y * BM;
  const int bn = blockIdx.x * BN;
  const int wm = (wave >> 1) * 64;
  const int wn = (wave & 1) * 64;
  const int l15 = lane & 15;
  const int quad = lane >> 4;

  f32x4 acc[4][4];
#pragma unroll
  for (int i = 0; i < 4; ++i)
#pragma unroll
    for (int j = 0; j < 4; ++j) acc[i][j] = (f32x4){0.f, 0.f, 0.f, 0.f};

  // staging: chunk c in [0,512): LDS elems [c*8, c*8+8), global row=c>>2,
  // col=(c&3)*8. Thread tid takes chunks tid and tid+256; per-lane lds ptr is
  // wave-uniform-base + lane*16 by construction (global_load_lds constraint).
  const short* pa0 = A + (size_t)(bm + (tid >> 2)) * K + (tid & 3) * 8;
  const short* pa1 = pa0 + (size_t)64 * K;
  const short* pb0 = Bt + (size_t)(bn + (tid >> 2)) * K + (tid & 3) * 8;
  const short* pb1 = pb0 + (size_t)64 * K;
  short* la0 = As + tid * 8;
  short* la1 = As + tid * 8 + 2048;
  short* lb0 = Bs + tid * 8;
  short* lb1 = Bs + tid * 8 + 2048;

  for (int kt = 0; kt < K; kt += BK) {
    GLD16(pa0, la0);
    GLD16(pa1, la1);
    GLD16(pb0, lb0);
    GLD16(pb1, lb1);
    pa0 += BK; pa1 += BK; pb0 += BK; pb1 += BK;
    __syncthreads();  // drains vmcnt (global_load_lds) before LDS reads

    bf16x8 af[4], bfr[4];
#pragma unroll
    for (int i = 0; i < 4; ++i)
      af[i] = *(const bf16x8*)(As + (wm + i * 16 + l15) * BK + quad * 8);
#pragma unroll
    for (int j = 0; j < 4; ++j)
      bfr[j] = *(const bf16x8*)(Bs + (wn + j * 16 + l15) * BK + quad * 8);

#pragma unroll
    for (int i = 0; i < 4; ++i)
#pragma unroll
      for (int j = 0; j < 4; ++j)
        acc[i][j] = __builtin_amdgcn_mfma_f32_16x16x32_bf16(
            af[i], bfr[j], acc[i][j], 0, 0, 0);
    __syncthreads();
  }

  // epilogue: C/D layout col=lane&15, row=(lane>>4)*4+reg (verified m89/m91)
#pragma unroll
  for (int j = 0; j < 4; ++j) {
    const int col = bn + wn + j * 16 + l15;
    const float bb = BF16_OUT ? 0.f : bias[col];
#pragma unroll
    for (int i = 0; i < 4; ++i) {
      const int row0 = bm + wm + i * 16 + quad * 4;
#pragma unroll
      for (int r = 0; r < 4; ++r) {
        float v = acc[i][j][r] * scale + bb;
        if (BF16_OUT)
          ((short*)Cout)[(size_t)(row0 + r) * N + col] = f2bf(v);
        else
          ((float*)Cout)[(size_t)(row0 + r) * N + col] = v;
      }
    }
  }
}

extern "C" void kernel_launch(void* const* d_in, const int* in_sizes, int n_in,
                              void* d_out, int out_size, void* d_ws,
                              size_t ws_size, hipStream_t stream) {
  // setup_inputs order: x, encoder_x, Wq, bq, Wk, bk, Wv, bv, Wo, bo
  const float* x  = (const float*)d_in[0];
  const float* Wv = (const float*)d_in[6];
  const float* bv = (const float*)d_in[7];
  const float* Wo = (const float*)d_in[8];
  const float* bo = (const float*)d_in[9];
  float* out = (float*)d_out;

  constexpr int L = 2048, D = 1024, NO = 1024;  // NO = H*QKV
  constexpr int M = 4 * L;                      // B*L = 8192

  char* ws = (char*)d_ws;
  short* x_bf   = (short*)(ws);                       // 16 MB: x as bf16
  short* wv_bf  = (short*)(ws + (16u << 20));         //  2 MB: Wv bf16
  short* wot_bf = (short*)(ws + (18u << 20));         //  2 MB: Wo^T bf16
  short* wt_bf  = (short*)(ws + (20u << 20));         //  2 MB: 2048*(Wv@Wo)^T
  float* biasc  = (float*)(ws + (22u << 20));         //  4 KB: fused bias

  // 1. casts (independent)
  cast_f32_bf16<<<(M * D / 8) / 256, 256, 0, stream>>>(x, x_bf, M * D / 8);
  cast_f32_bf16<<<(D * NO / 8) / 256, 256, 0, stream>>>(Wv, wv_bf, D * NO / 8);
  transpose_cast<<<dim3(16, 16), 256, 0, stream>>>(Wo, wot_bf, NO);
  bias_fuse<<<NO / 256, 256, 0, stream>>>(bv, Wo, bo, biasc, D, NO);

  // 2. Wt[n,k] = 2048*W[k,n]:  C[m,n] = sum_j Wo^T[m,j] * Wv[n,j]
  gemm_bt<true><<<dim3(NO / 128, NO / 128), 256, 0, stream>>>(
      wot_bf, wv_bf, nullptr, wt_bf, NO, NO, D, 2048.f);

  // 3. out = x @ W * 2048 + bias_c   (scale already folded into Wt)
  gemm_bt<false><<<dim3(NO / 128, M / 128), 256, 0, stream>>>(
      x_bf, wt_bf, biasc, out, M, NO, D, 1.f);
}

// Round 2
// 201.560 us; speedup vs baseline: 2.0906x; 2.0906x over previous
//
#include <hip/hip_runtime.h>
#include <stdint.h>

// ---------------------------------------------------------------------------
// CrossAttention_43061342110469 — algebraic reduction:
// einsum('bvhd,bhqk->bvhd', v, softmax(scores)) == v * L  (softmax rows sum
// to 1; summed over q gives L=2048). So out = 2048*(x @ Wv @ Wo) + const.
// encoder_x / Wq / bq / Wk / bk do not affect the output.
// ---------------------------------------------------------------------------

typedef __attribute__((ext_vector_type(8))) short bf16x8;
typedef __attribute__((ext_vector_type(4))) float f32x4;

typedef __attribute__((address_space(1))) void as1_void;
typedef __attribute__((address_space(3))) void as3_void;
#define GLD16(g, s)                                                          \
  __builtin_amdgcn_global_load_lds((as1_void*)(g), (as3_void*)(s), 16, 0, 0)

__device__ __forceinline__ short f2bf(float f) {
  union { float f; uint32_t u; } v; v.f = f;
  uint32_t r = v.u + 0x7FFFu + ((v.u >> 16) & 1u);  // round-to-nearest-even
  return (short)(r >> 16);
}

// ---- fp32 -> bf16 cast, 8 elems/thread, fully vectorized -------------------
__global__ __launch_bounds__(256) void cast_f32_bf16(
    const float* __restrict__ in, short* __restrict__ out, int n8) {
  int i = blockIdx.x * blockDim.x + threadIdx.x;
  if (i >= n8) return;
  const float4* p = (const float4*)in;
  float4 a = p[2 * (size_t)i], b = p[2 * (size_t)i + 1];
  bf16x8 o;
  o[0] = f2bf(a.x); o[1] = f2bf(a.y); o[2] = f2bf(a.z); o[3] = f2bf(a.w);
  o[4] = f2bf(b.x); o[5] = f2bf(b.y); o[6] = f2bf(b.z); o[7] = f2bf(b.w);
  *(bf16x8*)(out + 8 * (size_t)i) = o;
}

// ---- 1024x1024 fp32 -> bf16 transpose-cast (64x64 tiles via LDS) -----------
__global__ __launch_bounds__(256) void transpose_cast(
    const float* __restrict__ in, short* __restrict__ out, int n) {
  __shared__ float tile[64][65];
  const int br = blockIdx.y * 64;  // input row base
  const int bc = blockIdx.x * 64;  // input col base
  const int tid = threadIdx.x;
#pragma unroll
  for (int t = 0; t < 16; ++t) {
    int idx = t * 256 + tid;
    int r = idx >> 6, c = idx & 63;
    tile[r][c] = in[(size_t)(br + r) * n + bc + c];
  }
  __syncthreads();
#pragma unroll
  for (int t = 0; t < 16; ++t) {
    int idx = t * 256 + tid;
    int r = idx >> 6, c = idx & 63;  // output row = bc+r (orig col)
    out[(size_t)(bc + r) * n + br + c] = f2bf(tile[c][r]);
  }
}

// ---- bias_c[n] = 2048 * sum_k bv[k]*Wo[k,n] + bo[n] ------------------------
// 64 blocks x 256 thr: 16 outputs/block, 16 k-lanes/output + LDS tree reduce.
// (v1 used 4 blocks with a 1024-deep serial loop -> 240 us latency-bound.)
__global__ __launch_bounds__(256) void bias_fuse(
    const float* __restrict__ bv, const float* __restrict__ Wo,
    const float* __restrict__ bo, float* __restrict__ biasc, int D, int N) {
  __shared__ float red[256];
  const int tid = threadIdx.x;
  const int nx = tid & 15, ky = tid >> 4;
  const int n = blockIdx.x * 16 + nx;
  float s = 0.f;
  for (int k = ky; k < D; k += 16)
    s += bv[k] * Wo[(size_t)k * N + n];
  red[tid] = s;
  __syncthreads();
#pragma unroll
  for (int st = 128; st >= 16; st >>= 1) {
    if (tid < st) red[tid] += red[tid + st];
    __syncthreads();
  }
  if (ky == 0) biasc[n] = 2048.0f * red[nx] + bo[n];
}

// ---- C = A @ Bt^T  (Bt given row-major [N,K]); m97-style MFMA GEMM ---------
// BM=BN=128, BK=32, 256 threads (4 waves), each wave a 64x64 sub-tile as a
// 4x4 grid of 16x16x32 bf16 MFMAs. Staging via global_load_lds width=16.
// BF16_OUT: store bf16 with *scale (no bias). Else: fp32 with + bias[col].
template <bool BF16_OUT>
__global__ __launch_bounds__(256) void gemm_bt(
    const short* __restrict__ A, const short* __restrict__ Bt,
    const float* __restrict__ bias, void* __restrict__ Cout,
    int M, int N, int K, float scale) {
  constexpr int BM = 128, BN = 128, BK = 32;
  __shared__ __align__(16) short As[BM * BK];
  __shared__ __align__(16) short Bs[BN * BK];

  const int tid = threadIdx.x;
  const int lane = tid & 63;
  const int wave = tid >> 6;
  const int bm = blockIdx.y * BM;
  const int bn = blockIdx.x * BN;
  const int wm = (wave >> 1) * 64;
  const int wn = (wave & 1) * 64;
  const int l15 = lane & 15;
  const int quad = lane >> 4;

  f32x4 acc[4][4];
#pragma unroll
  for (int i = 0; i < 4; ++i)
#pragma unroll
    for (int j = 0; j < 4; ++j) acc[i][j] = (f32x4){0.f, 0.f, 0.f, 0.f};

  // staging: chunk c in [0,512): LDS elems [c*8, c*8+8), global row=c>>2,
  // col=(c&3)*8. Thread tid takes chunks tid and tid+256; per-lane lds ptr is
  // wave-uniform-base + lane*16 by construction (global_load_lds constraint).
  const short* pa0 = A + (size_t)(bm + (tid >> 2)) * K + (tid & 3) * 8;
  const short* pa1 = pa0 + (size_t)64 * K;
  const short* pb0 = Bt + (size_t)(bn + (tid >> 2)) * K + (tid & 3) * 8;
  const short* pb1 = pb0 + (size_t)64 * K;
  short* la0 = As + tid * 8;
  short* la1 = As + tid * 8 + 2048;
  short* lb0 = Bs + tid * 8;
  short* lb1 = Bs + tid * 8 + 2048;

  for (int kt = 0; kt < K; kt += BK) {
    GLD16(pa0, la0);
    GLD16(pa1, la1);
    GLD16(pb0, lb0);
    GLD16(pb1, lb1);
    pa0 += BK; pa1 += BK; pb0 += BK; pb1 += BK;
    __syncthreads();  // drains vmcnt (global_load_lds) before LDS reads

    bf16x8 af[4], bfr[4];
#pragma unroll
    for (int i = 0; i < 4; ++i)
      af[i] = *(const bf16x8*)(As + (wm + i * 16 + l15) * BK + quad * 8);
#pragma unroll
    for (int j = 0; j < 4; ++j)
      bfr[j] = *(const bf16x8*)(Bs + (wn + j * 16 + l15) * BK + quad * 8);

#pragma unroll
    for (int i = 0; i < 4; ++i)
#pragma unroll
      for (int j = 0; j < 4; ++j)
        acc[i][j] = __builtin_amdgcn_mfma_f32_16x16x32_bf16(
            af[i], bfr[j], acc[i][j], 0, 0, 0);
    __syncthreads();
  }

  // epilogue: C/D layout col=lane&15, row=(lane>>4)*4+reg (verified m89/m91)
#pragma unroll
  for (int j = 0; j < 4; ++j) {
    const int col = bn + wn + j * 16 + l15;
    const float bb = BF16_OUT ? 0.f : bias[col];
#pragma unroll
    for (int i = 0; i < 4; ++i) {
      const int row0 = bm + wm + i * 16 + quad * 4;
#pragma unroll
      for (int r = 0; r < 4; ++r) {
        float v = acc[i][j][r] * scale + bb;
        if (BF16_OUT)
          ((short*)Cout)[(size_t)(row0 + r) * N + col] = f2bf(v);
        else
          ((float*)Cout)[(size_t)(row0 + r) * N + col] = v;
      }
    }
  }
}

extern "C" void kernel_launch(void* const* d_in, const int* in_sizes, int n_in,
                              void* d_out, int out_size, void* d_ws,
                              size_t ws_size, hipStream_t stream) {
  // setup_inputs order: x, encoder_x, Wq, bq, Wk, bk, Wv, bv, Wo, bo
  const float* x  = (const float*)d_in[0];
  const float* Wv = (const float*)d_in[6];
  const float* bv = (const float*)d_in[7];
  const float* Wo = (const float*)d_in[8];
  const float* bo = (const float*)d_in[9];
  float* out = (float*)d_out;

  constexpr int L = 2048, D = 1024, NO = 1024;  // NO = H*QKV
  constexpr int M = 4 * L;                      // B*L = 8192

  char* ws = (char*)d_ws;
  short* x_bf   = (short*)(ws);                       // 16 MB: x as bf16
  short* wv_bf  = (short*)(ws + (16u << 20));         //  2 MB: Wv bf16
  short* wot_bf = (short*)(ws + (18u << 20));         //  2 MB: Wo^T bf16
  short* wt_bf  = (short*)(ws + (20u << 20));         //  2 MB: 2048*(Wv@Wo)^T
  float* biasc  = (float*)(ws + (22u << 20));         //  4 KB: fused bias

  // 1. casts (independent)
  cast_f32_bf16<<<(M * D / 8) / 256, 256, 0, stream>>>(x, x_bf, M * D / 8);
  cast_f32_bf16<<<(D * NO / 8) / 256, 256, 0, stream>>>(Wv, wv_bf, D * NO / 8);
  transpose_cast<<<dim3(16, 16), 256, 0, stream>>>(Wo, wot_bf, NO);
  bias_fuse<<<NO / 16, 256, 0, stream>>>(bv, Wo, bo, biasc, D, NO);

  // 2. Wt[n,k] = 2048*W[k,n]:  C[m,n] = sum_j Wo^T[m,j] * Wv[n,j]
  gemm_bt<true><<<dim3(NO / 128, NO / 128), 256, 0, stream>>>(
      wot_bf, wv_bf, nullptr, wt_bf, NO, NO, D, 2048.f);

  // 3. out = x @ W * 2048 + bias_c   (scale already folded into Wt)
  gemm_bt<false><<<dim3(NO / 128, M / 128), 256, 0, stream>>>(
      x_bf, wt_bf, biasc, out, M, NO, D, 1.f);
}

// Round 3
// 188.721 us; speedup vs baseline: 2.2328x; 1.0680x over previous
//
#include <hip/hip_runtime.h>
#include <stdint.h>

// ---------------------------------------------------------------------------
// CrossAttention_43061342110469 — algebraic reduction:
// einsum('bvhd,bhqk->bvhd', v, softmax(scores)) == v * L  (softmax rows sum
// to 1; summed over q gives L=2048). So out = 2048*(x @ Wv @ Wo) + const.
// encoder_x / Wq / bq / Wk / bk do not affect the output.
// ---------------------------------------------------------------------------

typedef __attribute__((ext_vector_type(8))) short bf16x8;
typedef __attribute__((ext_vector_type(4))) float f32x4;

typedef __attribute__((address_space(1))) void as1_void;
typedef __attribute__((address_space(3))) void as3_void;
#define GLD16(g, s)                                                          \
  __builtin_amdgcn_global_load_lds((as1_void*)(g), (as3_void*)(s), 16, 0, 0)

__device__ __forceinline__ short f2bf(float f) {
  union { float f; uint32_t u; } v; v.f = f;
  uint32_t r = v.u + 0x7FFFu + ((v.u >> 16) & 1u);  // round-to-nearest-even
  return (short)(r >> 16);
}

// ---- fp32 -> bf16 cast, 8 elems/thread, fully vectorized -------------------
__global__ __launch_bounds__(256) void cast_f32_bf16(
    const float* __restrict__ in, short* __restrict__ out, int n8) {
  int i = blockIdx.x * blockDim.x + threadIdx.x;
  if (i >= n8) return;
  const float4* p = (const float4*)in;
  float4 a = p[2 * (size_t)i], b = p[2 * (size_t)i + 1];
  bf16x8 o;
  o[0] = f2bf(a.x); o[1] = f2bf(a.y); o[2] = f2bf(a.z); o[3] = f2bf(a.w);
  o[4] = f2bf(b.x); o[5] = f2bf(b.y); o[6] = f2bf(b.z); o[7] = f2bf(b.w);
  *(bf16x8*)(out + 8 * (size_t)i) = o;
}

// ---- 1024x1024 fp32 -> bf16 transpose-cast (64x64 tiles via LDS) -----------
__global__ __launch_bounds__(256) void transpose_cast(
    const float* __restrict__ in, short* __restrict__ out, int n) {
  __shared__ float tile[64][65];
  const int br = blockIdx.y * 64;  // input row base
  const int bc = blockIdx.x * 64;  // input col base
  const int tid = threadIdx.x;
#pragma unroll
  for (int t = 0; t < 16; ++t) {
    int idx = t * 256 + tid;
    int r = idx >> 6, c = idx & 63;
    tile[r][c] = in[(size_t)(br + r) * n + bc + c];
  }
  __syncthreads();
#pragma unroll
  for (int t = 0; t < 16; ++t) {
    int idx = t * 256 + tid;
    int r = idx >> 6, c = idx & 63;  // output row = bc+r (orig col)
    out[(size_t)(bc + r) * n + br + c] = f2bf(tile[c][r]);
  }
}

// ---- bias_c[n] = 2048 * sum_k bv[k]*Wo[k,n] + bo[n] ------------------------
// 64 blocks x 256 thr: 16 outputs/block, 16 k-lanes/output + LDS tree reduce.
__global__ __launch_bounds__(256) void bias_fuse(
    const float* __restrict__ bv, const float* __restrict__ Wo,
    const float* __restrict__ bo, float* __restrict__ biasc, int D, int N) {
  __shared__ float red[256];
  const int tid = threadIdx.x;
  const int nx = tid & 15, ky = tid >> 4;
  const int n = blockIdx.x * 16 + nx;
  float s = 0.f;
  for (int k = ky; k < D; k += 16)
    s += bv[k] * Wo[(size_t)k * N + n];
  red[tid] = s;
  __syncthreads();
#pragma unroll
  for (int st = 128; st >= 16; st >>= 1) {
    if (tid < st) red[tid] += red[tid + st];
    __syncthreads();
  }
  if (ky == 0) biasc[n] = 2048.0f * red[nx] + bo[n];
}

// ---- C = A @ Bt^T  (Bt row-major [N,K]); m97-style MFMA GEMM, BK=64 --------
// BM=BN=128, BK=64, 256 threads (4 waves), each wave 64x64 as 4x4 grid of
// 16x16x32 bf16 MFMAs, 2 inner k-steps per tile. global_load_lds width=16.
// XOR swizzle on chunk assignment: LDS[row][c8] holds global chunk
// [row][c8 ^ (row&7)] -> ds_read_b128 frag reads spread over all 32 banks
// (2-way alias only = free), while the global side stays fully coalesced
// (per 8-thread row group the 8 chunks are just permuted within 128 B).
// PARTIAL: grid.z = split-K slice, fp32 partial store at Cout + z*M*N.
// Else: fp32 store with + bias[col].
template <bool PARTIAL>
__global__ __launch_bounds__(256) void gemm_bt(
    const short* __restrict__ A, const short* __restrict__ Bt,
    const float* __restrict__ bias, float* __restrict__ Cout,
    int M, int N, int K, int klen) {
  constexpr int BM = 128, BN = 128, BK = 64;
  __shared__ __align__(16) short As[BM * BK];
  __shared__ __align__(16) short Bs[BN * BK];

  const int tid = threadIdx.x;
  const int lane = tid & 63;
  const int wave = tid >> 6;
  const int bm = blockIdx.y * BM;
  const int bn = blockIdx.x * BN;
  const int k0 = blockIdx.z * klen;
  const int wm = (wave >> 1) * 64;
  const int wn = (wave & 1) * 64;
  const int l15 = lane & 15;
  const int quad = lane >> 4;

  f32x4 acc[4][4];
#pragma unroll
  for (int i = 0; i < 4; ++i)
#pragma unroll
    for (int j = 0; j < 4; ++j) acc[i][j] = (f32x4){0.f, 0.f, 0.f, 0.f};

  // staging: 1024 chunks of 8 shorts per operand tile (128 rows x 8 chunks).
  // thread tid stages chunk (row=tid>>3, c8=(tid&7)^(row&7)) + 3 more rows
  // at +32/+64/+96. LDS dst = tid*16 B (+4 KB steps): wave-uniform base +
  // lane*16 as global_load_lds requires.
  const int srow = tid >> 3;
  const int sc8 = (tid & 7) ^ (srow & 7);
  const short* pa = A + (size_t)(bm + srow) * K + k0 + sc8 * 8;
  const short* pb = Bt + (size_t)(bn + srow) * K + k0 + sc8 * 8;
  short* la = As + tid * 8;
  short* lb = Bs + tid * 8;

  for (int kt = 0; kt < klen; kt += BK) {
#pragma unroll
    for (int s = 0; s < 4; ++s) {
      GLD16(pa + (size_t)(32 * s) * K, la + 2048 * s);
      GLD16(pb + (size_t)(32 * s) * K, lb + 2048 * s);
    }
    pa += BK; pb += BK;
    __syncthreads();  // drains vmcnt (global_load_lds) before LDS reads

#pragma unroll
    for (int kk = 0; kk < 2; ++kk) {
      bf16x8 af[4], bfr[4];
#pragma unroll
      for (int i = 0; i < 4; ++i) {
        const int r = wm + i * 16 + l15;
        af[i] = *(const bf16x8*)(As + r * BK + ((kk * 4 + quad) ^ (r & 7)) * 8);
      }
#pragma unroll
      for (int j = 0; j < 4; ++j) {
        const int r = wn + j * 16 + l15;
        bfr[j] = *(const bf16x8*)(Bs + r * BK + ((kk * 4 + quad) ^ (r & 7)) * 8);
      }
#pragma unroll
      for (int i = 0; i < 4; ++i)
#pragma unroll
        for (int j = 0; j < 4; ++j)
          acc[i][j] = __builtin_amdgcn_mfma_f32_16x16x32_bf16(
              af[i], bfr[j], acc[i][j], 0, 0, 0);
    }
    __syncthreads();
  }

  // epilogue: C/D layout col=lane&15, row=(lane>>4)*4+reg (verified m89/m91)
  float* outp = PARTIAL ? Cout + (size_t)blockIdx.z * M * N : Cout;
#pragma unroll
  for (int j = 0; j < 4; ++j) {
    const int col = bn + wn + j * 16 + l15;
    const float bb = PARTIAL ? 0.f : bias[col];
#pragma unroll
    for (int i = 0; i < 4; ++i) {
      const int row0 = bm + wm + i * 16 + quad * 4;
#pragma unroll
      for (int r = 0; r < 4; ++r)
        outp[(size_t)(row0 + r) * N + col] = acc[i][j][r] + bb;
    }
  }
}

// ---- sum 4 split-K fp32 partials, scale by 2048, cast to bf16 --------------
__global__ __launch_bounds__(256) void reduce_cast(
    const float* __restrict__ part, short* __restrict__ out, int mn) {
  int i = blockIdx.x * blockDim.x + threadIdx.x;  // float4 index
  if (i >= mn / 4) return;
  const float4* p = (const float4*)part;
  const int st = mn / 4;
  float4 a = p[i], b = p[i + st], c = p[i + 2 * st], d = p[i + 3 * st];
  short4 o;
  o.x = f2bf(2048.f * (a.x + b.x + c.x + d.x));
  o.y = f2bf(2048.f * (a.y + b.y + c.y + d.y));
  o.z = f2bf(2048.f * (a.z + b.z + c.z + d.z));
  o.w = f2bf(2048.f * (a.w + b.w + c.w + d.w));
  ((short4*)out)[i] = o;
}

extern "C" void kernel_launch(void* const* d_in, const int* in_sizes, int n_in,
                              void* d_out, int out_size, void* d_ws,
                              size_t ws_size, hipStream_t stream) {
  // setup_inputs order: x, encoder_x, Wq, bq, Wk, bk, Wv, bv, Wo, bo
  const float* x  = (const float*)d_in[0];
  const float* Wv = (const float*)d_in[6];
  const float* bv = (const float*)d_in[7];
  const float* Wo = (const float*)d_in[8];
  const float* bo = (const float*)d_in[9];
  float* out = (float*)d_out;

  constexpr int L = 2048, D = 1024, NO = 1024;  // NO = H*QKV
  constexpr int M = 4 * L;                      // B*L = 8192

  char* ws = (char*)d_ws;
  short* x_bf   = (short*)(ws);                       // 16 MB: x as bf16
  short* wv_bf  = (short*)(ws + (16u << 20));         //  2 MB: Wv bf16
  short* wot_bf = (short*)(ws + (18u << 20));         //  2 MB: Wo^T bf16
  short* wt_bf  = (short*)(ws + (20u << 20));         //  2 MB: 2048*(Wv@Wo)^T
  float* biasc  = (float*)(ws + (22u << 20));         //  4 KB: fused bias
  float* wpart  = (float*)(ws + (24u << 20));         // 16 MB: split-K partials

  // 1. casts + bias (independent)
  cast_f32_bf16<<<(M * D / 8) / 256, 256, 0, stream>>>(x, x_bf, M * D / 8);
  cast_f32_bf16<<<(D * NO / 8) / 256, 256, 0, stream>>>(Wv, wv_bf, D * NO / 8);
  transpose_cast<<<dim3(16, 16), 256, 0, stream>>>(Wo, wot_bf, NO);
  bias_fuse<<<NO / 16, 256, 0, stream>>>(bv, Wo, bo, biasc, D, NO);

  // 2. Wt[n,k] = 2048*W[k,n] via split-K=4 (256 blocks = full chip) + reduce
  gemm_bt<true><<<dim3(NO / 128, NO / 128, 4), 256, 0, stream>>>(
      wot_bf, wv_bf, nullptr, wpart, NO, NO, D, D / 4);
  reduce_cast<<<(NO * NO / 4) / 256, 256, 0, stream>>>(wpart, wt_bf, NO * NO);

  // 3. out = x @ Wt^T + bias_c   (2048 scale folded into Wt)
  gemm_bt<false><<<dim3(NO / 128, M / 128, 1), 256, 0, stream>>>(
      x_bf, wt_bf, biasc, out, M, NO, D, D);
}